// Round 2
// baseline (110.386 us; speedup 1.0000x reference)
//
#include <hip/hip_runtime.h>
#include <math.h>

#define Bv 4
#define Nv 512
#define Dv 128
#define BND (Bv*Nv*Dv)      // 262144
#define NN  (Nv*Nv)         // 262144
#define EPSv 1e-9f

typedef float f4 __attribute__((ext_vector_type(4)));
typedef float f2 __attribute__((ext_vector_type(2)));

__device__ __forceinline__ f2 lo2(f4 v){ return __builtin_shufflevector(v, v, 0, 1); }
__device__ __forceinline__ f2 hi2(f4 v){ return __builtin_shufflevector(v, v, 2, 3); }

__device__ __forceinline__ f2 pk_add(f2 a, f2 b){
    f2 d; asm("v_pk_add_f32 %0, %1, %2" : "=v"(d) : "v"(a), "v"(b)); return d;
}
__device__ __forceinline__ f2 relu2(f2 z){
#if __has_builtin(__builtin_elementwise_max)
    return __builtin_elementwise_max(z, (f2)0.0f);
#else
    z.x = fmaxf(z.x, 0.0f); z.y = fmaxf(z.y, 0.0f); return z;
#endif
}
// acc += z * broadcast(a.lo)   (src1 low half feeds both lanes via op_sel)
__device__ __forceinline__ void pk_fma_lo(f2& acc, f2 z, f2 a){
    asm("v_pk_fma_f32 %0, %1, %2, %0 op_sel:[0,0,0] op_sel_hi:[1,0,1]"
        : "+v"(acc) : "v"(z), "v"(a));
}
// acc += z * broadcast(a.hi)
__device__ __forceinline__ void pk_fma_hi(f2& acc, f2 z, f2 a){
    asm("v_pk_fma_f32 %0, %1, %2, %0 op_sel:[0,1,0] op_sel_hi:[1,1,1]"
        : "+v"(acc) : "v"(z), "v"(a));
}

// -------------------------------------------------------------------------
// k_prep (unchanged from R5): gumbel-softmax + proj + s'/t with __logf/__expf.
// L2-bound on weight streams (~48 MB) — near its floor, left alone.
// -------------------------------------------------------------------------
__global__ __launch_bounds__(256) void k_prep(
    const float* __restrict__ ES, const float* __restrict__ Wp,
    const float* __restrict__ bp, const float* __restrict__ W1,
    const float* __restrict__ b1, const float* __restrict__ EL,
    const float* __restrict__ UN,
    float* __restrict__ s_out, float* __restrict__ t_out,
    float* __restrict__ A_out)
{
    __shared__ float es[4][Dv];
    __shared__ float pr[4][Dv];
    __shared__ float sred[4];
    const int bi = blockIdx.x;        // 0..511
    const int t  = threadIdx.x;

    // ---- phase A: softmax((EL+gumbel)/TAU) for row bi, broadcast to 4 b's
    {
        const int row = bi;
        const float u0 = UN[row*Nv + t];
        const float u1 = UN[row*Nv + t + 256];
        const float g0 = -__logf(-__logf(u0 + EPSv) + EPSv);
        const float g1 = -__logf(-__logf(u1 + EPSv) + EPSv);
        const float z0 = (EL[row*Nv + t]       + g0) * 2.0f;   // 1/TAU = 2
        const float z1 = (EL[row*Nv + t + 256] + g1) * 2.0f;

        float m = fmaxf(z0, z1);
        #pragma unroll
        for (int off = 32; off >= 1; off >>= 1)
            m = fmaxf(m, __shfl_xor(m, off, 64));
        if ((t & 63) == 0) sred[t >> 6] = m;
        __syncthreads();
        m = fmaxf(fmaxf(sred[0], sred[1]), fmaxf(sred[2], sred[3]));

        const float e0 = __expf(z0 - m);
        const float e1 = __expf(z1 - m);
        float ssum = e0 + e1;
        #pragma unroll
        for (int off = 32; off >= 1; off >>= 1)
            ssum += __shfl_xor(ssum, off, 64);
        __syncthreads();
        if ((t & 63) == 0) sred[t >> 6] = ssum;
        __syncthreads();
        const float inv = 1.0f / (sred[0] + sred[1] + sred[2] + sred[3]);
        const float a0 = e0 * inv;
        const float a1 = e1 * inv;
        #pragma unroll
        for (int bb = 0; bb < Bv; ++bb) {
            A_out[bb*NN + row*Nv + t]       = a0;
            A_out[bb*NN + row*Nv + t + 256] = a1;
        }
    }

    // ---- phase B: proj for rows bi*4 .. bi*4+3
    const int row0 = bi * 4;
    const int c  = t & 127;
    const int rg = t >> 7;            // 0..1 -> rows rg*2, rg*2+1

    for (int idx = t; idx < 4*Dv; idx += 256)
        es[idx >> 7][idx & 127] = ES[(row0 + (idx >> 7))*Dv + (idx & 127)];
    __syncthreads();

    {
        float acc[2];
        const float bpc = bp[c];
        acc[0] = bpc; acc[1] = bpc;
        #pragma unroll 8
        for (int k = 0; k < Dv; ++k) {
            const float w = Wp[k*Dv + c];
            acc[0] = fmaf(es[rg*2][k],   w, acc[0]);
            acc[1] = fmaf(es[rg*2+1][k], w, acc[1]);
        }
        pr[rg*2][c]   = acc[0];
        pr[rg*2+1][c] = acc[1];
    }
    __syncthreads();

    // ---- phase C: s' = proj@W1_src + b1, t = proj@W1_tgt
    float sacc0 = b1[c], sacc1 = sacc0, tacc0 = 0.0f, tacc1 = 0.0f;
    #pragma unroll 8
    for (int k = 0; k < Dv; ++k) {
        const float ws_ = W1[k*Dv + c];
        const float wt_ = W1[(Dv + k)*Dv + c];
        const float p0 = pr[rg*2][k];
        const float p1 = pr[rg*2+1][k];
        sacc0 = fmaf(p0, ws_, sacc0);
        sacc1 = fmaf(p1, ws_, sacc1);
        tacc0 = fmaf(p0, wt_, tacc0);
        tacc1 = fmaf(p1, wt_, tacc1);
    }
    const int ra = (row0 + rg*2)*Dv + c;
    s_out[ra]      = sacc0;
    s_out[ra + Dv] = sacc1;
    t_out[ra]      = tacc0;
    t_out[ra + Dv] = tacc1;
}

// -------------------------------------------------------------------------
// k_main R6: same shape as R5 (512 thr, 2 waves/SIMD, 1 iter-ahead sv
// prefetch) but the j-loop is packed-FP32:
//   v_pk_add_f32 + 2x v_max_f32 + v_pk_fma_f32 with op_sel broadcast of the
//   A scalar -> 8 instr / (r,j-quad... per f4) vs 12 scalar (-33% VALU).
// Wave-level jg-fold via shfl_xor(32) before LDS partials: part 64->32 KB,
// reduction reads halve. Epilogue GEMM also pk. LDS total 52 KB.
// -------------------------------------------------------------------------
__global__ __launch_bounds__(512, 2) void k_main(
    const float* __restrict__ s_buf, const float* __restrict__ t_buf,
    const float* __restrict__ A0,    const float* __restrict__ ES,
    const float* __restrict__ W2,    const float* __restrict__ b2,
    float* __restrict__ out)
{
    __shared__ float A_lds[8][Nv];     // 16 KB
    __shared__ f4    part[8][8][32];   // 32 KB [wave][i][dq]
    __shared__ float hsum[8][Dv];      // 4 KB
    const int i0 = blockIdx.x * 8;
    const int b  = blockIdx.y;
    const int t  = threadIdx.x;
    const int dq = t & 31;             // d = dq*4 .. dq*4+3
    const int jg = t >> 5;             // 0..15 -> j in [jg*32, jg*32+32)

    // stage A rows i0..i0+7 (b-independent copy 0), coalesced f4
    {
        const f4* __restrict__ src = (const f4*)(A0 + i0*Nv);
        f4* dst = (f4*)(&A_lds[0][0]);
        dst[t]       = src[t];
        dst[t + 512] = src[t + 512];
    }

    f2 tvL[8], tvH[8];
    #pragma unroll
    for (int r = 0; r < 8; ++r) {
        const f4 tv = *(const f4*)(t_buf + (b*Nv + i0 + r)*Dv + dq*4);
        tvL[r] = lo2(tv); tvH[r] = hi2(tv);
    }

    f2 accL[8], accH[8];
    #pragma unroll
    for (int r = 0; r < 8; ++r) { accL[r] = (f2)0.0f; accH[r] = (f2)0.0f; }

    __syncthreads();                   // A_lds ready

    const float* __restrict__ sb = s_buf + (size_t)b*Nv*Dv + dq*4;
    const int j0 = jg * 32;

    // prefetch first j4 quad
    f4 svn0 = *(const f4*)(sb + (j0+0)*Dv);
    f4 svn1 = *(const f4*)(sb + (j0+1)*Dv);
    f4 svn2 = *(const f4*)(sb + (j0+2)*Dv);
    f4 svn3 = *(const f4*)(sb + (j0+3)*Dv);

    #pragma unroll
    for (int jj = 0; jj < 32; jj += 4) {
        const int j4 = j0 + jj;
        const f2 s0L = lo2(svn0), s0H = hi2(svn0);
        const f2 s1L = lo2(svn1), s1H = hi2(svn1);
        const f2 s2L = lo2(svn2), s2H = hi2(svn2);
        const f2 s3L = lo2(svn3), s3H = hi2(svn3);
        if (jj < 28) {                 // compile-time under full unroll
            svn0 = *(const f4*)(sb + (j4+4)*Dv);
            svn1 = *(const f4*)(sb + (j4+5)*Dv);
            svn2 = *(const f4*)(sb + (j4+6)*Dv);
            svn3 = *(const f4*)(sb + (j4+7)*Dv);
        }
        f4 a[8];
        #pragma unroll
        for (int r = 0; r < 8; ++r)
            a[r] = *(const f4*)(&A_lds[r][j4]);   // b128 bcast/2-way, free
        #pragma unroll
        for (int r = 0; r < 8; ++r) {
            const f2 a01 = lo2(a[r]), a23 = hi2(a[r]);
            pk_fma_lo(accL[r], relu2(pk_add(s0L, tvL[r])), a01);
            pk_fma_lo(accH[r], relu2(pk_add(s0H, tvH[r])), a01);
            pk_fma_hi(accL[r], relu2(pk_add(s1L, tvL[r])), a01);
            pk_fma_hi(accH[r], relu2(pk_add(s1H, tvH[r])), a01);
            pk_fma_lo(accL[r], relu2(pk_add(s2L, tvL[r])), a23);
            pk_fma_lo(accH[r], relu2(pk_add(s2H, tvH[r])), a23);
            pk_fma_hi(accL[r], relu2(pk_add(s3L, tvL[r])), a23);
            pk_fma_hi(accH[r], relu2(pk_add(s3H, tvH[r])), a23);
        }
    }

    // fold the wave's two jg halves (lane l <-> l+32): same dq, adjacent jg
    #pragma unroll
    for (int r = 0; r < 8; ++r) {
        accL[r].x += __shfl_xor(accL[r].x, 32, 64);
        accL[r].y += __shfl_xor(accL[r].y, 32, 64);
        accH[r].x += __shfl_xor(accH[r].x, 32, 64);
        accH[r].y += __shfl_xor(accH[r].y, 32, 64);
    }
    {
        const int lane = t & 63;
        const int wv   = t >> 6;       // 0..7
        if (lane < 32) {
            #pragma unroll
            for (int r = 0; r < 8; ++r) {
                f4 v = { accL[r].x, accL[r].y, accH[r].x, accH[r].y };
                part[wv][r][dq] = v;   // dq == lane here
            }
        }
    }
    __syncthreads();
    if (t < 256) {
        const int ri = t >> 5;         // 0..7
        f4 s = part[0][ri][dq];
        #pragma unroll
        for (int g = 1; g < 8; ++g) s += part[g][ri][dq];
        *(f4*)(&hsum[ri][dq*4]) = s;
    }
    __syncthreads();

    // epilogue: out = ES + hsum@W2 + b2; thread = (1 row rr, 2 cols), pk
    const int cg = t & 63;
    const int rr = t >> 6;             // 0..7
    const int c0 = 2*cg;
    f2 o = { b2[c0], b2[c0+1] };
    #pragma unroll 8
    for (int k4 = 0; k4 < Dv; k4 += 4) {
        const f4 h = *(const f4*)(&hsum[rr][k4]);  // b128 broadcast
        const f2 h01 = lo2(h), h23 = hi2(h);
        const f2 w0 = *(const f2*)(W2 + (k4+0)*Dv + c0);
        const f2 w1 = *(const f2*)(W2 + (k4+1)*Dv + c0);
        const f2 w2 = *(const f2*)(W2 + (k4+2)*Dv + c0);
        const f2 w3 = *(const f2*)(W2 + (k4+3)*Dv + c0);
        pk_fma_lo(o, w0, h01);
        pk_fma_hi(o, w1, h01);
        pk_fma_lo(o, w2, h23);
        pk_fma_hi(o, w3, h23);
    }
    const int ro = (b*Nv + i0 + rr)*Dv + c0;
    const float2 e = *(const float2*)(ES + ro);
    float2 v; v.x = e.x + o.x; v.y = e.y + o.y;
    *(float2*)(out + ro) = v;
}

extern "C" void kernel_launch(void* const* d_in, const int* in_sizes, int n_in,
                              void* d_out, int out_size, void* d_ws, size_t ws_size,
                              hipStream_t stream) {
    (void)in_sizes; (void)n_in; (void)out_size; (void)ws_size;
    const float* ES = (const float*)d_in[0];
    const float* Wp = (const float*)d_in[1];
    const float* bp = (const float*)d_in[2];
    const float* EL = (const float*)d_in[3];
    const float* W1 = (const float*)d_in[4];
    const float* b1 = (const float*)d_in[5];
    const float* W2 = (const float*)d_in[6];
    const float* b2 = (const float*)d_in[7];
    const float* UN = (const float*)d_in[8];

    float* out   = (float*)d_out;
    float* A_out = out + BND;            // A broadcast region: B*N*N floats

    float* s_buf = (float*)d_ws;         // s' = proj@W1_src + b1  (B*N*D)
    float* t_buf = s_buf + BND;          // t  = proj@W1_tgt       (B*N*D)

    k_prep<<<512, 256, 0, stream>>>(ES, Wp, bp, W1, b1, EL, UN,
                                    s_buf, t_buf, A_out);
    k_main<<<dim3(Nv/8, Bv), 512, 0, stream>>>(s_buf, t_buf, A_out, ES, W2, b2,
                                               out);
}

// Round 3
// 99.104 us; speedup vs baseline: 1.1138x; 1.1138x over previous
//
#include <hip/hip_runtime.h>
#include <math.h>

#define Bv 4
#define Nv 512
#define Dv 128
#define BND (Bv*Nv*Dv)      // 262144
#define NN  (Nv*Nv)         // 262144
#define EPSv 1e-9f

typedef float f4 __attribute__((ext_vector_type(4)));
typedef float f2 __attribute__((ext_vector_type(2)));

__device__ __forceinline__ f2 relu2(f2 z) {
#if __has_builtin(__builtin_elementwise_max)
    return __builtin_elementwise_max(z, (f2)0.0f);
#else
    z.x = fmaxf(z.x, 0.0f); z.y = fmaxf(z.y, 0.0f); return z;
#endif
}

// -------------------------------------------------------------------------
// k_prep (unchanged from R5, known-good): gumbel-softmax + proj + s'/t with
// __logf/__expf. Grid 512 x 256 thr -> 2 blocks/CU.
// -------------------------------------------------------------------------
__global__ __launch_bounds__(256) void k_prep(
    const float* __restrict__ ES, const float* __restrict__ Wp,
    const float* __restrict__ bp, const float* __restrict__ W1,
    const float* __restrict__ b1, const float* __restrict__ EL,
    const float* __restrict__ UN,
    float* __restrict__ s_out, float* __restrict__ t_out,
    float* __restrict__ A_out)
{
    __shared__ float es[4][Dv];
    __shared__ float pr[4][Dv];
    __shared__ float sred[4];
    const int bi = blockIdx.x;        // 0..511
    const int t  = threadIdx.x;

    // ---- phase A: softmax((EL+gumbel)/TAU) for row bi, broadcast to 4 b's
    {
        const int row = bi;
        const float u0 = UN[row*Nv + t];
        const float u1 = UN[row*Nv + t + 256];
        const float g0 = -__logf(-__logf(u0 + EPSv) + EPSv);
        const float g1 = -__logf(-__logf(u1 + EPSv) + EPSv);
        const float z0 = (EL[row*Nv + t]       + g0) * 2.0f;   // 1/TAU = 2
        const float z1 = (EL[row*Nv + t + 256] + g1) * 2.0f;

        float m = fmaxf(z0, z1);
        #pragma unroll
        for (int off = 32; off >= 1; off >>= 1)
            m = fmaxf(m, __shfl_xor(m, off, 64));
        if ((t & 63) == 0) sred[t >> 6] = m;
        __syncthreads();
        m = fmaxf(fmaxf(sred[0], sred[1]), fmaxf(sred[2], sred[3]));

        const float e0 = __expf(z0 - m);
        const float e1 = __expf(z1 - m);
        float ssum = e0 + e1;
        #pragma unroll
        for (int off = 32; off >= 1; off >>= 1)
            ssum += __shfl_xor(ssum, off, 64);
        __syncthreads();
        if ((t & 63) == 0) sred[t >> 6] = ssum;
        __syncthreads();
        const float inv = 1.0f / (sred[0] + sred[1] + sred[2] + sred[3]);
        const float a0 = e0 * inv;
        const float a1 = e1 * inv;
        #pragma unroll
        for (int bb = 0; bb < Bv; ++bb) {
            A_out[bb*NN + row*Nv + t]       = a0;
            A_out[bb*NN + row*Nv + t + 256] = a1;
        }
    }

    // ---- phase B: proj for rows bi*4 .. bi*4+3
    const int row0 = bi * 4;
    const int c  = t & 127;
    const int rg = t >> 7;            // 0..1 -> rows rg*2, rg*2+1

    for (int idx = t; idx < 4*Dv; idx += 256)
        es[idx >> 7][idx & 127] = ES[(row0 + (idx >> 7))*Dv + (idx & 127)];
    __syncthreads();

    {
        float acc[2];
        const float bpc = bp[c];
        acc[0] = bpc; acc[1] = bpc;
        #pragma unroll 8
        for (int k = 0; k < Dv; ++k) {
            const float w = Wp[k*Dv + c];
            acc[0] = fmaf(es[rg*2][k],   w, acc[0]);
            acc[1] = fmaf(es[rg*2+1][k], w, acc[1]);
        }
        pr[rg*2][c]   = acc[0];
        pr[rg*2+1][c] = acc[1];
    }
    __syncthreads();

    // ---- phase C: s' = proj@W1_src + b1, t = proj@W1_tgt
    float sacc0 = b1[c], sacc1 = sacc0, tacc0 = 0.0f, tacc1 = 0.0f;
    #pragma unroll 8
    for (int k = 0; k < Dv; ++k) {
        const float ws_ = W1[k*Dv + c];
        const float wt_ = W1[(Dv + k)*Dv + c];
        const float p0 = pr[rg*2][k];
        const float p1 = pr[rg*2+1][k];
        sacc0 = fmaf(p0, ws_, sacc0);
        sacc1 = fmaf(p1, ws_, sacc1);
        tacc0 = fmaf(p0, wt_, tacc0);
        tacc1 = fmaf(p1, wt_, tacc1);
    }
    const int ra = (row0 + rg*2)*Dv + c;
    s_out[ra]      = sacc0;
    s_out[ra + Dv] = sacc1;
    t_out[ra]      = tacc0;
    t_out[ra + Dv] = tacc1;
}

// -------------------------------------------------------------------------
// k_main R7: f2-wide thread layout, 1024 thr/block, grid (64,4) = 1 blk/CU
// -> 16 waves/block = 4 waves/SIMD (2x R5's latency hiding), same total
// VALU work and same per-block L2 traffic (sv still read once per block;
// lanes 0..63 = the 64 d-pairs -> 512B coalesced b64 loads).
// Arithmetic kept as C-level f2 vector ops so ISel may form
// v_pk_add_f32/v_pk_fma_f32 (gfx90a+ patterns); if it scalarizes we
// degenerate to exactly R5's scalar stream (no downside). NO inline asm
// (R6 lesson: asm blocked scheduling/regalloc, -8us).
// A_lds reads are full-wave broadcast (whole wave shares one jg).
// LDS: A 16K + part 32K + hsum 4K = 52 KB. VGPR est ~92 under the 128 cap
// from __launch_bounds__(1024,4).
// -------------------------------------------------------------------------
__global__ __launch_bounds__(1024, 4) void k_main(
    const float* __restrict__ s_buf, const float* __restrict__ t_buf,
    const float* __restrict__ A0,    const float* __restrict__ ES,
    const float* __restrict__ W2,    const float* __restrict__ b2,
    float* __restrict__ out)
{
    __shared__ float A_lds[8][Nv];     // 16 KB
    __shared__ f2    part[16][8][64];  // 32 KB [jg][i][dh]
    __shared__ float hsum[8][Dv];      // 4 KB
    const int i0 = blockIdx.x * 8;
    const int b  = blockIdx.y;
    const int t  = threadIdx.x;
    const int dh = t & 63;             // d = dh*2, dh*2+1
    const int jg = t >> 6;             // 0..15 -> j in [jg*32, jg*32+32)

    // stage A rows i0..i0+7 (b-independent copy 0), coalesced f4, 1/thread
    {
        const f4* __restrict__ src = (const f4*)(A0 + i0*Nv);
        f4* dst = (f4*)(&A_lds[0][0]);
        dst[t] = src[t];
    }

    f2 tv[8];
    #pragma unroll
    for (int r = 0; r < 8; ++r)
        tv[r] = *(const f2*)(t_buf + (b*Nv + i0 + r)*Dv + dh*2);

    f2 acc[8];
    #pragma unroll
    for (int r = 0; r < 8; ++r) acc[r] = (f2)0.0f;

    __syncthreads();                   // A_lds ready

    const float* __restrict__ sb = s_buf + (size_t)b*Nv*Dv + dh*2;
    const int j0 = jg * 32;

    // prefetch first j4 quad (b64 loads)
    f2 svn0 = *(const f2*)(sb + (j0+0)*Dv);
    f2 svn1 = *(const f2*)(sb + (j0+1)*Dv);
    f2 svn2 = *(const f2*)(sb + (j0+2)*Dv);
    f2 svn3 = *(const f2*)(sb + (j0+3)*Dv);

    #pragma unroll
    for (int jj = 0; jj < 32; jj += 4) {
        const int j4 = j0 + jj;
        const f2 sv0 = svn0, sv1 = svn1, sv2 = svn2, sv3 = svn3;
        if (jj < 28) {                 // compile-time under full unroll
            svn0 = *(const f2*)(sb + (j4+4)*Dv);
            svn1 = *(const f2*)(sb + (j4+5)*Dv);
            svn2 = *(const f2*)(sb + (j4+6)*Dv);
            svn3 = *(const f2*)(sb + (j4+7)*Dv);
        }
        f4 a[8];
        #pragma unroll
        for (int r = 0; r < 8; ++r)
            a[r] = *(const f4*)(&A_lds[r][j4]);   // wave-broadcast, free
        #pragma unroll
        for (int r = 0; r < 8; ++r) {
            acc[r] += relu2(sv0 + tv[r]) * (f2)(a[r][0]);
            acc[r] += relu2(sv1 + tv[r]) * (f2)(a[r][1]);
            acc[r] += relu2(sv2 + tv[r]) * (f2)(a[r][2]);
            acc[r] += relu2(sv3 + tv[r]) * (f2)(a[r][3]);
        }
    }

    // jg-partials -> LDS, reduce 16-way
    #pragma unroll
    for (int r = 0; r < 8; ++r) part[jg][r][dh] = acc[r];
    __syncthreads();
    if (t < 512) {
        const int ri = t >> 6;         // 0..7
        f2 s = part[0][ri][dh];
        #pragma unroll
        for (int g = 1; g < 16; ++g) s += part[g][ri][dh];
        *(f2*)(&hsum[ri][dh*2]) = s;
    }
    __syncthreads();

    // epilogue: out = ES + hsum@W2 + b2; thread = (1 row rr, 1 col c)
    const int c  = t & 127;
    const int rr = t >> 7;             // 0..7
    float o = b2[c];
    #pragma unroll 8
    for (int k4 = 0; k4 < Dv; k4 += 4) {
        const f4 h = *(const f4*)(&hsum[rr][k4]);  // b128 wave-broadcast
        o = fmaf(h[0], W2[(k4+0)*Dv + c], o);
        o = fmaf(h[1], W2[(k4+1)*Dv + c], o);
        o = fmaf(h[2], W2[(k4+2)*Dv + c], o);
        o = fmaf(h[3], W2[(k4+3)*Dv + c], o);
    }
    const int ro = (b*Nv + i0 + rr)*Dv + c;
    out[ro] = ES[ro] + o;
}

extern "C" void kernel_launch(void* const* d_in, const int* in_sizes, int n_in,
                              void* d_out, int out_size, void* d_ws, size_t ws_size,
                              hipStream_t stream) {
    (void)in_sizes; (void)n_in; (void)out_size; (void)ws_size;
    const float* ES = (const float*)d_in[0];
    const float* Wp = (const float*)d_in[1];
    const float* bp = (const float*)d_in[2];
    const float* EL = (const float*)d_in[3];
    const float* W1 = (const float*)d_in[4];
    const float* b1 = (const float*)d_in[5];
    const float* W2 = (const float*)d_in[6];
    const float* b2 = (const float*)d_in[7];
    const float* UN = (const float*)d_in[8];

    float* out   = (float*)d_out;
    float* A_out = out + BND;            // A broadcast region: B*N*N floats

    float* s_buf = (float*)d_ws;         // s' = proj@W1_src + b1  (B*N*D)
    float* t_buf = s_buf + BND;          // t  = proj@W1_tgt       (B*N*D)

    k_prep<<<512, 256, 0, stream>>>(ES, Wp, bp, W1, b1, EL, UN,
                                    s_buf, t_buf, A_out);
    k_main<<<dim3(Nv/8, Bv), 1024, 0, stream>>>(s_buf, t_buf, A_out, ES, W2, b2,
                                                out);
}